// Round 4
// baseline (742.365 us; speedup 1.0000x reference)
//
#include <hip/hip_runtime.h>
#include <hip/hip_cooperative_groups.h>

namespace cg = cooperative_groups;

#define B_   256
#define I_   1152
#define N_   10
#define P_   9216      // 8 * 1152
#define NO_  160       // 10 * 16

typedef unsigned short u16;
typedef short s8v __attribute__((ext_vector_type(8)));
typedef float f4v __attribute__((ext_vector_type(4)));

__device__ inline float bf2f(u16 u){
  unsigned v = ((unsigned)u) << 16; float f; __builtin_memcpy(&f, &v, 4); return f;
}
__device__ inline u16 f2bf(float f){
  unsigned b; __builtin_memcpy(&b, &f, 4);
  b += 0x7fffu + ((b >> 16) & 1u);   // RNE
  return (u16)(b >> 16);
}

// ---------------------------------------------------------------------------
// Phase device functions — shared between the cooperative fused kernel and
// the standalone fallback kernels. `u` = block-unit index, `w` = wave-unit.

// prep: u in [0,2464). u<160: W[i][n][o][k] -> Wt[q][p]=bf16(0.03W),
// At=bf16(0.003W) (iter-0 c=0.1); u<45 also zeroes bij. u>=160: x fp32 ->
// bf16 xbp[b][p] + xpb[p][b] (LDS 32x32 transpose).
__device__ __forceinline__ void dev_prep(int u, int t,
    const float* __restrict__ x, const float* __restrict__ W,
    u16* __restrict__ xbp, u16* __restrict__ xpb,
    u16* __restrict__ Wt, u16* __restrict__ At,
    float* __restrict__ bij, float (*tile)[36])
{
  if (u < 160){
    if (u < 45) bij[u*256 + t] = 0.f;
    int q = u, n = q >> 4, o = q & 15;
    for (int i0 = 0; i0 < I_; i0 += 256){
      int i = i0 + t;
      if (i < I_){
        const float* src = W + (size_t)i*1280 + n*128 + o*8;
        float4 a = *reinterpret_cast<const float4*>(src);
        float4 b = *reinterpret_cast<const float4*>(src + 4);
        float vv[8] = {a.x,a.y,a.z,a.w,b.x,b.y,b.z,b.w};
        #pragma unroll
        for (int k = 0; k < 8; ++k){
          size_t addr = (size_t)q*P_ + (size_t)k*I_ + i;
          float wv = vv[k] * 0.03f;
          Wt[addr] = f2bf(wv);
          At[addr] = f2bf(wv * 0.1f);
        }
      }
    }
  } else {
    int b2 = u - 160;
    int tb = b2 & 7, tp = b2 >> 3;
    int b0 = tb << 5, p0 = tp << 5;
    int r = t >> 3, c4 = (t & 7) << 2;
    __syncthreads();                       // WAR guard on tile reuse
    float4 v = *reinterpret_cast<const float4*>(x + (size_t)(b0 + r)*P_ + p0 + c4);
    *reinterpret_cast<float4*>(&tile[r][c4]) = v;
    uint2 pk;
    pk.x = (unsigned)f2bf(v.x) | ((unsigned)f2bf(v.y) << 16);
    pk.y = (unsigned)f2bf(v.z) | ((unsigned)f2bf(v.w) << 16);
    *reinterpret_cast<uint2*>(xbp + (size_t)(b0 + r)*P_ + p0 + c4) = pk;
    __syncthreads();
    float f0 = tile[c4+0][r], f1 = tile[c4+1][r], f2 = tile[c4+2][r], f3 = tile[c4+3][r];
    uint2 pk2;
    pk2.x = (unsigned)f2bf(f0) | ((unsigned)f2bf(f1) << 16);
    pk2.y = (unsigned)f2bf(f2) | ((unsigned)f2bf(f3) << 16);
    *reinterpret_cast<uint2*>(xpb + (size_t)(p0 + r)*B_ + b0 + c4) = pk2;
  }
}

// gemm_s: w in [0,2560) = 16 kc x 10 n x 16 b-tiles. One wave per 16x16 tile.
// s_part[kc][b][q] = sum_{p in chunk kc} xbp[b][p] * At[q][p]
__device__ __forceinline__ void dev_gemm_s(int w, int l,
    const u16* __restrict__ xbp, const u16* __restrict__ At,
    float* __restrict__ s_part)
{
  int kc = w / 160, r2 = w - kc*160;
  int n = r2 >> 4, bx = r2 & 15;
  int b0 = bx << 4;
  int lo = l & 15, quad = l >> 4;
  const s8v* ap = reinterpret_cast<const s8v*>(xbp + (size_t)(b0 + lo)*P_ + kc*576 + quad*8);
  const s8v* bp = reinterpret_cast<const s8v*>(At  + (size_t)(n*16 + lo)*P_ + kc*576 + quad*8);
  f4v acc0 = {0.f,0.f,0.f,0.f}, acc1 = {0.f,0.f,0.f,0.f};
  #pragma unroll
  for (int s = 0; s < 9; ++s){
    s8v a0 = ap[8*s],     b0v = bp[8*s];
    s8v a1 = ap[8*s + 4], b1v = bp[8*s + 4];
    acc0 = __builtin_amdgcn_mfma_f32_16x16x32_bf16(a0, b0v, acc0, 0, 0, 0);
    acc1 = __builtin_amdgcn_mfma_f32_16x16x32_bf16(a1, b1v, acc1, 0, 0, 0);
  }
  f4v acc = acc0 + acc1;
  float* op = s_part + (size_t)kc*40960;
  int r0 = quad << 2;
  #pragma unroll
  for (int r = 0; r < 4; ++r)
    op[(size_t)(b0 + r0 + r)*NO_ + n*16 + lo] = acc[r];
}

// squash: u in [0,160). Reduce 16 split-K partials, squash over O per (b,n),
// write fp32 out and bf16 v^T[q][b].
__device__ __forceinline__ void dev_squash(int u, int t,
    const float* __restrict__ s_part, float* __restrict__ out,
    u16* __restrict__ vbt)
{
  int o = t & 15, rl = t >> 4;
  int rowid = u*16 + rl;                   // b*10+n
  int b = rowid / 10, n = rowid - b*10;
  size_t idx = (size_t)b*NO_ + n*16 + o;
  float sv = 0.f;
  #pragma unroll
  for (int c = 0; c < 16; ++c) sv += s_part[idx + (size_t)c*40960];
  float sq = sv * sv;
  #pragma unroll
  for (int m = 8; m >= 1; m >>= 1) sq += __shfl_xor(sq, m, 16);
  float outv = sv * sqrtf(sq) / (1.0f + sq);
  out[idx] = outv;                         // final iteration's write survives
  vbt[(size_t)(n*16 + o)*B_ + b] = f2bf(outv);
}

// gemm_g + bij dot: w in [0,2880) = 576 p-tiles x 5 q-pairs. No G matrix
// materialized: G fragment * Wt fragment, shuffle-sum over o-lanes,
// atomicAdd into bij[i][n] (device-scope; accumulates across iterations).
__device__ __forceinline__ void dev_gemm_g(int w, int l,
    const u16* __restrict__ xpb, const u16* __restrict__ vbt,
    const u16* __restrict__ Wt, float* __restrict__ bij)
{
  int pt = w % 576, qp = w / 576;
  int p0 = pt << 4;
  int lo = l & 15, quad = l >> 4;
  const s8v* ap  = reinterpret_cast<const s8v*>(xpb + (size_t)(p0 + lo)*B_ + quad*8);
  const s8v* bp0 = reinterpret_cast<const s8v*>(vbt + (size_t)((qp*2+0)*16 + lo)*B_ + quad*8);
  const s8v* bp1 = reinterpret_cast<const s8v*>(vbt + (size_t)((qp*2+1)*16 + lo)*B_ + quad*8);
  f4v acc0 = {0.f,0.f,0.f,0.f}, acc1 = {0.f,0.f,0.f,0.f};
  #pragma unroll
  for (int s = 0; s < 8; ++s){
    s8v a  = ap[4*s];
    s8v b0 = bp0[4*s];
    s8v b1 = bp1[4*s];
    acc0 = __builtin_amdgcn_mfma_f32_16x16x32_bf16(a, b0, acc0, 0, 0, 0);
    acc1 = __builtin_amdgcn_mfma_f32_16x16x32_bf16(a, b1, acc1, 0, 0, 0);
  }
  int ib = p0 % 1152;                      // p-tile never spans k (1152%16==0)
  #pragma unroll
  for (int s = 0; s < 2; ++s){
    f4v acc = s ? acc1 : acc0;
    int n = qp*2 + s;
    const u16* wp = Wt + (size_t)(n*16 + lo)*P_ + p0 + (quad << 2);
    ushort4 w4 = *reinterpret_cast<const ushort4*>(wp);
    float v0 = acc[0]*bf2f(w4.x), v1 = acc[1]*bf2f(w4.y);
    float v2 = acc[2]*bf2f(w4.z), v3 = acc[3]*bf2f(w4.w);
    #pragma unroll
    for (int m = 8; m >= 1; m >>= 1){
      v0 += __shfl_xor(v0, m, 16);
      v1 += __shfl_xor(v1, m, 16);
      v2 += __shfl_xor(v2, m, 16);
      v3 += __shfl_xor(v3, m, 16);
    }
    if (lo == 0){
      int i = ib + (quad << 2);
      atomicAdd(&bij[(i+0)*N_ + n], v0 * (1.f/256.f));
      atomicAdd(&bij[(i+1)*N_ + n], v1 * (1.f/256.f));
      atomicAdd(&bij[(i+2)*N_ + n], v2 * (1.f/256.f));
      atomicAdd(&bij[(i+3)*N_ + n], v3 * (1.f/256.f));
    }
  }
}

// softmax + At = c*Wt: u in [0,720); each unit covers 2048 contiguous At
// elements (exactly one n = u/72). Redundant per-block softmax into LDS
// (UNPADDED c_pad: i0 multiple of 8 -> 32B-aligned float4 reads; the R3
// +1/8 padding made ds_read_b128 misaligned = UB, the round-3 bug).
__device__ __forceinline__ void dev_atmat(int u, int t,
    const float* __restrict__ bij, const u16* __restrict__ Wt,
    u16* __restrict__ At, float* __restrict__ c_pad)
{
  int n = u / 72;
  __syncthreads();                         // WAR guard on c_pad reuse
  for (int i = t; i < I_; i += 256){
    const float* br = bij + i*N_;
    float mx = br[0];
    #pragma unroll
    for (int nn = 1; nn < N_; ++nn) mx = fmaxf(mx, br[nn]);
    float se = 0.f, en = 0.f;
    #pragma unroll
    for (int nn = 0; nn < N_; ++nn){
      float e = __expf(br[nn] - mx);
      se += e;
      if (nn == n) en = e;
    }
    c_pad[i] = en / se;
  }
  __syncthreads();
  int base = (u*256 + t) * 8;
  int q = base / P_;
  int rem = base - q*P_;
  int k = rem / I_;
  int i0 = rem - k*I_;
  uint4 w = *reinterpret_cast<const uint4*>(Wt + base);
  float4 c0 = *reinterpret_cast<const float4*>(&c_pad[i0]);
  float4 c1 = *reinterpret_cast<const float4*>(&c_pad[i0 + 4]);
  uint4 r;
  r.x = (unsigned)f2bf(bf2f(w.x & 0xffff) * c0.x) | ((unsigned)f2bf(bf2f(w.x >> 16) * c0.y) << 16);
  r.y = (unsigned)f2bf(bf2f(w.y & 0xffff) * c0.z) | ((unsigned)f2bf(bf2f(w.y >> 16) * c0.w) << 16);
  r.z = (unsigned)f2bf(bf2f(w.z & 0xffff) * c1.x) | ((unsigned)f2bf(bf2f(w.z >> 16) * c1.y) << 16);
  r.w = (unsigned)f2bf(bf2f(w.w & 0xffff) * c1.z) | ((unsigned)f2bf(bf2f(w.w >> 16) * c1.w) << 16);
  *reinterpret_cast<uint4*>(At + base) = r;
}

// ---------------------------------------------------------------------------
// Cooperative fused kernel: all phases grid-stride (works for any gridDim),
// separated by grid.sync().
__global__ __launch_bounds__(256, 4) void caps_fused(
    const float* __restrict__ x, const float* __restrict__ W,
    float* __restrict__ out,
    u16* __restrict__ xbp, u16* __restrict__ xpb,
    u16* __restrict__ Wt,  u16* __restrict__ At,
    float* __restrict__ s_part, float* __restrict__ bij,
    u16* __restrict__ vbt)
{
  cg::grid_group grid = cg::this_grid();
  __shared__ float tile[32][36];
  __shared__ float c_pad[I_];
  const int t = threadIdx.x, bid = blockIdx.x, G = gridDim.x;
  const int l = t & 63, wv = t >> 6;

  for (int u = bid; u < 2464; u += G)
    dev_prep(u, t, x, W, xbp, xpb, Wt, At, bij, tile);
  grid.sync();

  for (int it = 0; it < 3; ++it){
    for (int w = bid*4 + wv; w < 2560; w += G*4)
      dev_gemm_s(w, l, xbp, At, s_part);
    grid.sync();
    for (int u = bid; u < 160; u += G)
      dev_squash(u, t, s_part, out, vbt);
    if (it == 2) break;
    grid.sync();
    for (int w = bid*4 + wv; w < 2880; w += G*4)
      dev_gemm_g(w, l, xpb, vbt, Wt, bij);
    grid.sync();
    for (int u = bid; u < 720; u += G)
      dev_atmat(u, t, bij, Wt, At, c_pad);
    grid.sync();
  }
}

// ---------------------------------------------------------------------------
// Standalone fallback kernels (used only if the cooperative launch errors).
__global__ void k_prep(const float* x, const float* W, u16* xbp, u16* xpb,
                       u16* Wt, u16* At, float* bij){
  __shared__ float tile[32][36];
  dev_prep(blockIdx.x, threadIdx.x, x, W, xbp, xpb, Wt, At, bij, tile);
}
__global__ void k_gemm_s(const u16* xbp, const u16* At, float* s_part){
  int w = blockIdx.x*4 + (threadIdx.x >> 6);
  dev_gemm_s(w, threadIdx.x & 63, xbp, At, s_part);      // grid 640
}
__global__ void k_squash(const float* s_part, float* out, u16* vbt){
  dev_squash(blockIdx.x, threadIdx.x, s_part, out, vbt); // grid 160
}
__global__ void k_gemm_g(const u16* xpb, const u16* vbt, const u16* Wt, float* bij){
  int w = blockIdx.x*4 + (threadIdx.x >> 6);
  dev_gemm_g(w, threadIdx.x & 63, xpb, vbt, Wt, bij);    // grid 720
}
__global__ void k_atmat(const float* bij, const u16* Wt, u16* At){
  __shared__ float c_pad[I_];
  dev_atmat(blockIdx.x, threadIdx.x, bij, Wt, At, c_pad); // grid 720
}

// ---------------------------------------------------------------------------
extern "C" void kernel_launch(void* const* d_in, const int* in_sizes, int n_in,
                              void* d_out, int out_size, void* d_ws, size_t ws_size,
                              hipStream_t stream){
  (void)in_sizes; (void)n_in; (void)out_size; (void)ws_size;
  const float* x = (const float*)d_in[0];   // (256, 8, 1152)
  const float* W = (const float*)d_in[1];   // (1, 1152, 10, 16, 8)
  float* out = (float*)d_out;               // (256, 10, 16, 1)

  float* s_part = (float*)d_ws;             // 16 * 40960 fp32
  float* bij    = s_part + 16*40960;        // 11520 fp32
  u16* xbp = (u16*)(bij + 11520);           // 2359296 bf16
  u16* xpb = xbp + 2359296;                 // 2359296
  u16* Wt  = xpb + 2359296;                 // 1474560
  u16* At  = Wt  + 1474560;                 // 1474560
  u16* vbt = At  + 1474560;                 // 40960

  // Cooperative path: clamp grid to runtime-reported co-residency, verify
  // the launch result; otherwise run the conventional 11-dispatch path.
  int maxb = 0;
  hipError_t qe = hipOccupancyMaxActiveBlocksPerMultiprocessor(
      &maxb, (const void*)caps_fused, 256, 0);
  bool coop_ok = (qe == hipSuccess && maxb >= 1);
  if (coop_ok){
    int nblk = maxb * 256;
    if (nblk > 720) nblk = 720;
    void* args[] = {(void*)&x, (void*)&W, (void*)&out, (void*)&xbp, (void*)&xpb,
                    (void*)&Wt, (void*)&At, (void*)&s_part, (void*)&bij, (void*)&vbt};
    hipError_t le = hipLaunchCooperativeKernel((void*)caps_fused, dim3(nblk),
                                               dim3(256), args, 0, stream);
    coop_ok = (le == hipSuccess);
  }
  if (!coop_ok){
    k_prep<<<2464, 256, 0, stream>>>(x, W, xbp, xpb, Wt, At, bij);
    for (int it = 0; it < 3; ++it){
      k_gemm_s<<<640, 256, 0, stream>>>(xbp, At, s_part);
      k_squash<<<160, 256, 0, stream>>>(s_part, out, vbt);
      if (it < 2){
        k_gemm_g<<<720, 256, 0, stream>>>(xpb, vbt, Wt, bij);
        k_atmat<<<720, 256, 0, stream>>>(bij, Wt, At);
      }
    }
  }
}

// Round 5
// 171.240 us; speedup vs baseline: 4.3352x; 4.3352x over previous
//
#include <hip/hip_runtime.h>

#define B_   256
#define I_   1152
#define N_   10
#define P_   9216      // 8 * 1152
#define NO_  160       // 10 * 16

typedef unsigned short u16;
typedef short s8v __attribute__((ext_vector_type(8)));
typedef float f4v __attribute__((ext_vector_type(4)));

__device__ inline float bf2f(u16 u){
  unsigned v = ((unsigned)u) << 16; float f; __builtin_memcpy(&f, &v, 4); return f;
}
__device__ inline u16 f2bf(float f){
  unsigned b; __builtin_memcpy(&b, &f, 4);
  b += 0x7fffu + ((b >> 16) & 1u);   // RNE
  return (u16)(b >> 16);
}

// ---------------------------------------------------------------------------
// k_prep: grid 2464 x 256.
//   blocks [0,160):  W[i][n][o][k] -> Wt[q=n*16+o][p=k*1152+i] = bf16(0.03*W);
//                    blocks [0,45) also zero bij (softmax of 0 -> c = 0.1,
//                    so iteration 0 needs no special case).
//   blocks [160,2464): x fp32 [b][p] -> bf16 xbp[b][p] + xpb[p][b] (LDS transpose)
__global__ void k_prep(const float* __restrict__ x, const float* __restrict__ W,
                       u16* __restrict__ xbp, u16* __restrict__ xpb,
                       u16* __restrict__ Wt, float* __restrict__ bij){
  __shared__ float tile[32][36];
  int t = threadIdx.x, u = blockIdx.x;
  if (u < 160){
    if (u < 45) bij[u*256 + t] = 0.f;
    int q = u, n = q >> 4, o = q & 15;
    for (int i0 = 0; i0 < I_; i0 += 256){
      int i = i0 + t;
      if (i < I_){
        const float* src = W + (size_t)i*1280 + n*128 + o*8;
        float4 a = *reinterpret_cast<const float4*>(src);
        float4 b = *reinterpret_cast<const float4*>(src + 4);
        float vv[8] = {a.x,a.y,a.z,a.w,b.x,b.y,b.z,b.w};
        #pragma unroll
        for (int k = 0; k < 8; ++k)
          Wt[(size_t)q*P_ + (size_t)k*I_ + i] = f2bf(vv[k] * 0.03f);
      }
    }
  } else {
    int b2 = u - 160;
    int tb = b2 & 7, tp = b2 >> 3;
    int b0 = tb << 5, p0 = tp << 5;
    int r = t >> 3, c4 = (t & 7) << 2;
    float4 v = *reinterpret_cast<const float4*>(x + (size_t)(b0 + r)*P_ + p0 + c4);
    *reinterpret_cast<float4*>(&tile[r][c4]) = v;
    uint2 pk;
    pk.x = (unsigned)f2bf(v.x) | ((unsigned)f2bf(v.y) << 16);
    pk.y = (unsigned)f2bf(v.z) | ((unsigned)f2bf(v.w) << 16);
    *reinterpret_cast<uint2*>(xbp + (size_t)(b0 + r)*P_ + p0 + c4) = pk;
    __syncthreads();
    float f0 = tile[c4+0][r], f1 = tile[c4+1][r], f2 = tile[c4+2][r], f3 = tile[c4+3][r];
    uint2 pk2;
    pk2.x = (unsigned)f2bf(f0) | ((unsigned)f2bf(f1) << 16);
    pk2.y = (unsigned)f2bf(f2) | ((unsigned)f2bf(f3) << 16);
    *reinterpret_cast<uint2*>(xpb + (size_t)(p0 + r)*B_ + b0 + c4) = pk2;
  }
}

// ---------------------------------------------------------------------------
// k_sgemm: fused softmax + c-scaling + GEMM-S + squash.
// grid 160 (n = bid>>4, b-tile = bid&15), block 512 (8 waves).
// Phase 1: c_pad[i] = softmax_n(bij[i][:]) for this block's n (redundant/block).
// Phase 2: wave w handles K-chunk p in [w*1152,(w+1)*1152): 36 MFMA steps;
//          B fragment = bf16(bf2f(Wt) * c[i]) built in-register (numerically
//          identical to materializing At). i = p mod 1152 never wraps in-chunk.
// Phase 3: LDS cross-wave reduce (8 partials), squash over o per (b,n) row,
//          write fp32 out and bf16 v^T[q][b].
__global__ __launch_bounds__(512) void k_sgemm(
    const u16* __restrict__ xbp, const u16* __restrict__ Wt,
    const float* __restrict__ bij, float* __restrict__ out,
    u16* __restrict__ vbt){
  __shared__ float c_pad[I_];           // 4.6 KB
  __shared__ float sred[8*64*4];        // 8 KB
  int t = threadIdx.x;
  int n = blockIdx.x >> 4, bx = blockIdx.x & 15;
  int b0 = bx << 4;

  // phase 1: softmax over the 10 logits of each i, keep component n
  for (int i = t; i < I_; i += 512){
    const float* br = bij + i*N_;
    float l0 = br[0], l1 = br[1], l2 = br[2], l3 = br[3], l4 = br[4];
    float l5 = br[5], l6 = br[6], l7 = br[7], l8 = br[8], l9 = br[9];
    float mx = fmaxf(fmaxf(fmaxf(fmaxf(l0,l1),fmaxf(l2,l3)),fmaxf(fmaxf(l4,l5),fmaxf(l6,l7))),fmaxf(l8,l9));
    float e0=__expf(l0-mx), e1=__expf(l1-mx), e2=__expf(l2-mx), e3=__expf(l3-mx), e4=__expf(l4-mx);
    float e5=__expf(l5-mx), e6=__expf(l6-mx), e7=__expf(l7-mx), e8=__expf(l8-mx), e9=__expf(l9-mx);
    float se = e0+e1+e2+e3+e4+e5+e6+e7+e8+e9;
    float ev[10] = {e0,e1,e2,e3,e4,e5,e6,e7,e8,e9};
    c_pad[i] = ev[n] / se;
  }
  __syncthreads();

  // phase 2: MFMA K-loop with in-register B scaling
  int w = t >> 6, l = t & 63;
  int lo = l & 15, quad = l >> 4;
  const s8v* ap = reinterpret_cast<const s8v*>(xbp + (size_t)(b0 + lo)*P_ + w*1152 + quad*8);
  const u16* wp = Wt + (size_t)(n*16 + lo)*P_ + w*1152 + quad*8;
  f4v acc0 = {0.f,0.f,0.f,0.f}, acc1 = {0.f,0.f,0.f,0.f};
  #pragma unroll 4
  for (int s = 0; s < 36; ++s){
    int ib = s*32 + quad*8;             // i-base, multiple of 8, never wraps
    s8v a  = ap[4*s];
    s8v wv = *reinterpret_cast<const s8v*>(wp + 32*s);
    float4 c0 = *reinterpret_cast<const float4*>(&c_pad[ib]);
    float4 c1 = *reinterpret_cast<const float4*>(&c_pad[ib + 4]);
    s8v b;
    b[0] = (short)f2bf(bf2f((u16)wv[0]) * c0.x);
    b[1] = (short)f2bf(bf2f((u16)wv[1]) * c0.y);
    b[2] = (short)f2bf(bf2f((u16)wv[2]) * c0.z);
    b[3] = (short)f2bf(bf2f((u16)wv[3]) * c0.w);
    b[4] = (short)f2bf(bf2f((u16)wv[4]) * c1.x);
    b[5] = (short)f2bf(bf2f((u16)wv[5]) * c1.y);
    b[6] = (short)f2bf(bf2f((u16)wv[6]) * c1.z);
    b[7] = (short)f2bf(bf2f((u16)wv[7]) * c1.w);
    if (s & 1) acc1 = __builtin_amdgcn_mfma_f32_16x16x32_bf16(a, b, acc1, 0, 0, 0);
    else       acc0 = __builtin_amdgcn_mfma_f32_16x16x32_bf16(a, b, acc0, 0, 0, 0);
  }
  f4v acc = acc0 + acc1;
  *reinterpret_cast<f4v*>(&sred[(w*64 + l)*4]) = acc;
  __syncthreads();

  // phase 3: cross-wave reduce + squash
  if (t < 256){
    int row = t >> 4, o = t & 15;       // b = b0+row (C-layout row=quad*4+r)
    int qd = row >> 2, r = row & 3;
    float sv = 0.f;
    #pragma unroll
    for (int ww = 0; ww < 8; ++ww)
      sv += sred[(ww*64 + qd*16 + o)*4 + r];
    float sq = sv * sv;
    #pragma unroll
    for (int m = 8; m >= 1; m >>= 1) sq += __shfl_xor(sq, m, 16);
    float outv = sv * sqrtf(sq) / (1.0f + sq);
    int b = b0 + row;
    out[(size_t)b*NO_ + n*16 + o] = outv;   // iter 0/1 writes overwritten by iter 2
    vbt[(size_t)(n*16 + o)*B_ + b] = f2bf(outv);
  }
}

// ---------------------------------------------------------------------------
// k_gemm_g: G^ [p][q] = sum_b xpb[p][b]*vbt[q][b] (never materialized);
// multiply by Wt fragment in-register, shuffle-sum over o-lanes,
// atomicAdd into bij[i][n]  (bij accumulates across iterations).
// grid 720 x 256 = 2880 wave-units (576 p-tiles x 5 q-pairs).
__global__ void k_gemm_g(const u16* __restrict__ xpb, const u16* __restrict__ vbt,
                         const u16* __restrict__ Wt, float* __restrict__ bij){
  int w = blockIdx.x*4 + (threadIdx.x >> 6);
  int l = threadIdx.x & 63;
  int pt = w % 576, qp = w / 576;
  int p0 = pt << 4;
  int lo = l & 15, quad = l >> 4;
  const s8v* ap  = reinterpret_cast<const s8v*>(xpb + (size_t)(p0 + lo)*B_ + quad*8);
  const s8v* bp0 = reinterpret_cast<const s8v*>(vbt + (size_t)((qp*2+0)*16 + lo)*B_ + quad*8);
  const s8v* bp1 = reinterpret_cast<const s8v*>(vbt + (size_t)((qp*2+1)*16 + lo)*B_ + quad*8);
  f4v acc0 = {0.f,0.f,0.f,0.f}, acc1 = {0.f,0.f,0.f,0.f};
  #pragma unroll
  for (int s = 0; s < 8; ++s){
    s8v a  = ap[4*s];
    s8v b0 = bp0[4*s];
    s8v b1 = bp1[4*s];
    acc0 = __builtin_amdgcn_mfma_f32_16x16x32_bf16(a, b0, acc0, 0, 0, 0);
    acc1 = __builtin_amdgcn_mfma_f32_16x16x32_bf16(a, b1, acc1, 0, 0, 0);
  }
  int ib = p0 % 1152;                   // p-tile never spans k (1152 % 16 == 0)
  #pragma unroll
  for (int s = 0; s < 2; ++s){
    f4v acc = s ? acc1 : acc0;
    int n = qp*2 + s;
    const u16* wp = Wt + (size_t)(n*16 + lo)*P_ + p0 + (quad << 2);
    ushort4 w4 = *reinterpret_cast<const ushort4*>(wp);
    float v0 = acc[0]*bf2f(w4.x), v1 = acc[1]*bf2f(w4.y);
    float v2 = acc[2]*bf2f(w4.z), v3 = acc[3]*bf2f(w4.w);
    #pragma unroll
    for (int m = 8; m >= 1; m >>= 1){
      v0 += __shfl_xor(v0, m, 16);
      v1 += __shfl_xor(v1, m, 16);
      v2 += __shfl_xor(v2, m, 16);
      v3 += __shfl_xor(v3, m, 16);
    }
    if (lo == 0){
      int i = ib + (quad << 2);
      atomicAdd(&bij[(i+0)*N_ + n], v0 * (1.f/256.f));
      atomicAdd(&bij[(i+1)*N_ + n], v1 * (1.f/256.f));
      atomicAdd(&bij[(i+2)*N_ + n], v2 * (1.f/256.f));
      atomicAdd(&bij[(i+3)*N_ + n], v3 * (1.f/256.f));
    }
  }
}

// ---------------------------------------------------------------------------
extern "C" void kernel_launch(void* const* d_in, const int* in_sizes, int n_in,
                              void* d_out, int out_size, void* d_ws, size_t ws_size,
                              hipStream_t stream){
  (void)in_sizes; (void)n_in; (void)out_size; (void)ws_size;
  const float* x = (const float*)d_in[0];   // (256, 8, 1152)
  const float* W = (const float*)d_in[1];   // (1, 1152, 10, 16, 8)
  float* out = (float*)d_out;               // (256, 10, 16, 1) fp32

  float* bij = (float*)d_ws;                // 11520 fp32
  u16* xbp = (u16*)(bij + 11520);           // 2359296 bf16
  u16* xpb = xbp + 2359296;                 // 2359296
  u16* Wt  = xpb + 2359296;                 // 1474560
  u16* vbt = Wt  + 1474560;                 // 40960

  k_prep<<<2464, 256, 0, stream>>>(x, W, xbp, xpb, Wt, bij);
  for (int it = 0; it < 3; ++it){
    k_sgemm<<<160, 512, 0, stream>>>(xbp, Wt, bij, out, vbt);
    if (it < 2)
      k_gemm_g<<<720, 256, 0, stream>>>(xpb, vbt, Wt, bij);
  }
}

// Round 6
// 152.479 us; speedup vs baseline: 4.8686x; 1.1230x over previous
//
#include <hip/hip_runtime.h>

#define B_   256
#define I_   1152
#define N_   10
#define P_   9216      // 8 * 1152
#define NO_  160       // 10 * 16

typedef unsigned short u16;
typedef short s8v __attribute__((ext_vector_type(8)));
typedef float f4v __attribute__((ext_vector_type(4)));

__device__ inline float bf2f(u16 u){
  unsigned v = ((unsigned)u) << 16; float f; __builtin_memcpy(&f, &v, 4); return f;
}
__device__ inline u16 f2bf(float f){
  unsigned b; __builtin_memcpy(&b, &f, 4);
  b += 0x7fffu + ((b >> 16) & 1u);   // RNE
  return (u16)(b >> 16);
}

// ---------------------------------------------------------------------------
// k_prep: grid 2464 x 256.
//   blocks [0,160):  W[i][n][o][k] -> Wt[q=n*16+o][p=k*1152+i]=bf16(0.03W) and
//                    At0 = bf16(0.003W)  (iter-0 c = 0.1 uniform);
//                    blocks [0,45) also zero bij.
//   blocks [160,2464): x fp32 [b][p] -> bf16 xbp[b][p] + xpb[p][b] (LDS transpose)
__global__ void k_prep(const float* __restrict__ x, const float* __restrict__ W,
                       u16* __restrict__ xbp, u16* __restrict__ xpb,
                       u16* __restrict__ Wt, u16* __restrict__ At,
                       float* __restrict__ bij){
  __shared__ float tile[32][36];
  int t = threadIdx.x, u = blockIdx.x;
  if (u < 160){
    if (u < 45) bij[u*256 + t] = 0.f;
    int q = u, n = q >> 4, o = q & 15;
    for (int i0 = 0; i0 < I_; i0 += 256){
      int i = i0 + t;
      if (i < I_){
        const float* src = W + (size_t)i*1280 + n*128 + o*8;
        float4 a = *reinterpret_cast<const float4*>(src);
        float4 b = *reinterpret_cast<const float4*>(src + 4);
        float vv[8] = {a.x,a.y,a.z,a.w,b.x,b.y,b.z,b.w};
        #pragma unroll
        for (int k = 0; k < 8; ++k){
          size_t addr = (size_t)q*P_ + (size_t)k*I_ + i;
          float wv = vv[k] * 0.03f;
          Wt[addr] = f2bf(wv);
          At[addr] = f2bf(wv * 0.1f);
        }
      }
    }
  } else {
    int b2 = u - 160;
    int tb = b2 & 7, tp = b2 >> 3;
    int b0 = tb << 5, p0 = tp << 5;
    int r = t >> 3, c4 = (t & 7) << 2;
    float4 v = *reinterpret_cast<const float4*>(x + (size_t)(b0 + r)*P_ + p0 + c4);
    *reinterpret_cast<float4*>(&tile[r][c4]) = v;
    uint2 pk;
    pk.x = (unsigned)f2bf(v.x) | ((unsigned)f2bf(v.y) << 16);
    pk.y = (unsigned)f2bf(v.z) | ((unsigned)f2bf(v.w) << 16);
    *reinterpret_cast<uint2*>(xbp + (size_t)(b0 + r)*P_ + p0 + c4) = pk;
    __syncthreads();
    float f0 = tile[c4+0][r], f1 = tile[c4+1][r], f2 = tile[c4+2][r], f3 = tile[c4+3][r];
    uint2 pk2;
    pk2.x = (unsigned)f2bf(f0) | ((unsigned)f2bf(f1) << 16);
    pk2.y = (unsigned)f2bf(f2) | ((unsigned)f2bf(f3) << 16);
    *reinterpret_cast<uint2*>(xpb + (size_t)(p0 + r)*B_ + b0 + c4) = pk2;
  }
}

// ---------------------------------------------------------------------------
// k_s: s_part[kc][b][q] = sum_p xbp[b][p] * At[q][p]  (MFMA 16x16x32 bf16)
// grid (16,10,16) x 64 — R2-proven shape: 2560 single-wave blocks, split-K 16,
// dual accumulators, fully unrolled 18-step K-loop.
__global__ void k_s(const u16* __restrict__ xbp, const u16* __restrict__ At,
                    float* __restrict__ s_part){
  int l = threadIdx.x;
  int b0 = blockIdx.x << 4;
  int n  = blockIdx.y;
  int kc = blockIdx.z;
  int lo = l & 15, quad = l >> 4;
  const s8v* ap = reinterpret_cast<const s8v*>(xbp + (size_t)(b0 + lo)*P_ + kc*576 + quad*8);
  const s8v* bp = reinterpret_cast<const s8v*>(At  + (size_t)(n*16 + lo)*P_ + kc*576 + quad*8);
  f4v acc0 = {0.f,0.f,0.f,0.f}, acc1 = {0.f,0.f,0.f,0.f};
  #pragma unroll
  for (int s = 0; s < 9; ++s){
    s8v a0 = ap[8*s],     b0v = bp[8*s];
    s8v a1 = ap[8*s + 4], b1v = bp[8*s + 4];
    acc0 = __builtin_amdgcn_mfma_f32_16x16x32_bf16(a0, b0v, acc0, 0, 0, 0);
    acc1 = __builtin_amdgcn_mfma_f32_16x16x32_bf16(a1, b1v, acc1, 0, 0, 0);
  }
  f4v acc = acc0 + acc1;
  float* op = s_part + (size_t)kc*40960;
  int r0 = quad << 2;
  #pragma unroll
  for (int r = 0; r < 4; ++r)
    op[(size_t)(b0 + r0 + r)*NO_ + n*16 + lo] = acc[r];
}

// ---------------------------------------------------------------------------
// k_sq: reduce 16 split-K partials, squash over O per (b,n) row (16-lane
// shuffle reduce), write fp32 out and bf16 v^T[q][b]. grid 160 x 256.
__global__ void k_sq(const float* __restrict__ s_part, float* __restrict__ out,
                     u16* __restrict__ vbt){
  int t = threadIdx.x;
  int o = t & 15, rl = t >> 4;
  int rowid = blockIdx.x*16 + rl;          // b*10+n
  int b = rowid / 10, n = rowid - b*10;
  size_t idx = (size_t)b*NO_ + n*16 + o;
  float sv = 0.f;
  #pragma unroll
  for (int c = 0; c < 16; ++c) sv += s_part[idx + (size_t)c*40960];
  float sq = sv * sv;
  #pragma unroll
  for (int m = 8; m >= 1; m >>= 1) sq += __shfl_xor(sq, m, 16);
  float outv = sv * sqrtf(sq) / (1.0f + sq);
  out[idx] = outv;                         // final iteration's write survives
  vbt[(size_t)(n*16 + o)*B_ + b] = f2bf(outv);
}

// ---------------------------------------------------------------------------
// k_g: G[p][q] = sum_b xpb[p][b]*vbt[q][b] (never materialized); multiply by
// Wt fragment in-register, shuffle-sum over o-lanes, atomicAdd into bij[i][n]
// (accumulates across iterations). grid 720 x 256 = 2880 wave-units.
__global__ void k_g(const u16* __restrict__ xpb, const u16* __restrict__ vbt,
                    const u16* __restrict__ Wt, float* __restrict__ bij){
  int w = blockIdx.x*4 + (threadIdx.x >> 6);
  int l = threadIdx.x & 63;
  int pt = w % 576, qp = w / 576;
  int p0 = pt << 4;
  int lo = l & 15, quad = l >> 4;
  const s8v* ap  = reinterpret_cast<const s8v*>(xpb + (size_t)(p0 + lo)*B_ + quad*8);
  const s8v* bp0 = reinterpret_cast<const s8v*>(vbt + (size_t)((qp*2+0)*16 + lo)*B_ + quad*8);
  const s8v* bp1 = reinterpret_cast<const s8v*>(vbt + (size_t)((qp*2+1)*16 + lo)*B_ + quad*8);
  f4v acc0 = {0.f,0.f,0.f,0.f}, acc1 = {0.f,0.f,0.f,0.f};
  #pragma unroll
  for (int s = 0; s < 8; ++s){
    s8v a  = ap[4*s];
    s8v b0 = bp0[4*s];
    s8v b1 = bp1[4*s];
    acc0 = __builtin_amdgcn_mfma_f32_16x16x32_bf16(a, b0, acc0, 0, 0, 0);
    acc1 = __builtin_amdgcn_mfma_f32_16x16x32_bf16(a, b1, acc1, 0, 0, 0);
  }
  int ib = p0 % 1152;                      // p-tile never spans k (1152%16==0)
  #pragma unroll
  for (int s = 0; s < 2; ++s){
    f4v acc = s ? acc1 : acc0;
    int n = qp*2 + s;
    const u16* wp = Wt + (size_t)(n*16 + lo)*P_ + p0 + (quad << 2);
    ushort4 w4 = *reinterpret_cast<const ushort4*>(wp);
    float v0 = acc[0]*bf2f(w4.x), v1 = acc[1]*bf2f(w4.y);
    float v2 = acc[2]*bf2f(w4.z), v3 = acc[3]*bf2f(w4.w);
    #pragma unroll
    for (int m = 8; m >= 1; m >>= 1){
      v0 += __shfl_xor(v0, m, 16);
      v1 += __shfl_xor(v1, m, 16);
      v2 += __shfl_xor(v2, m, 16);
      v3 += __shfl_xor(v3, m, 16);
    }
    if (lo == 0){
      int i = ib + (quad << 2);
      atomicAdd(&bij[(i+0)*N_ + n], v0 * (1.f/256.f));
      atomicAdd(&bij[(i+1)*N_ + n], v1 * (1.f/256.f));
      atomicAdd(&bij[(i+2)*N_ + n], v2 * (1.f/256.f));
      atomicAdd(&bij[(i+3)*N_ + n], v3 * (1.f/256.f));
    }
  }
}

// ---------------------------------------------------------------------------
// k_at: softmax (per-block redundant, one n per block = bid/72) + At = c*Wt.
// grid 720 x 256; each block covers 2048 contiguous At elements, fully
// coalesced 16B lanes. c_pad unpadded (i0 multiple of 8 -> aligned float4).
__global__ void k_at(const float* __restrict__ bij, const u16* __restrict__ Wt,
                     u16* __restrict__ At){
  __shared__ float c_pad[I_];
  int t = threadIdx.x, u = blockIdx.x;
  int n = u / 72;
  for (int i = t; i < I_; i += 256){
    const float* br = bij + i*N_;
    float l0 = br[0], l1 = br[1], l2 = br[2], l3 = br[3], l4 = br[4];
    float l5 = br[5], l6 = br[6], l7 = br[7], l8 = br[8], l9 = br[9];
    float mx = fmaxf(fmaxf(fmaxf(fmaxf(l0,l1),fmaxf(l2,l3)),
                           fmaxf(fmaxf(l4,l5),fmaxf(l6,l7))), fmaxf(l8,l9));
    float e0=__expf(l0-mx), e1=__expf(l1-mx), e2=__expf(l2-mx), e3=__expf(l3-mx), e4=__expf(l4-mx);
    float e5=__expf(l5-mx), e6=__expf(l6-mx), e7=__expf(l7-mx), e8=__expf(l8-mx), e9=__expf(l9-mx);
    float se = e0+e1+e2+e3+e4+e5+e6+e7+e8+e9;
    float ev[10] = {e0,e1,e2,e3,e4,e5,e6,e7,e8,e9};
    c_pad[i] = ev[n] / se;
  }
  __syncthreads();
  int base = (u*256 + t) * 8;
  int rem = base % P_;
  int i0 = rem % I_;                       // multiple of 8
  uint4 w = *reinterpret_cast<const uint4*>(Wt + base);
  float4 c0 = *reinterpret_cast<const float4*>(&c_pad[i0]);
  float4 c1 = *reinterpret_cast<const float4*>(&c_pad[i0 + 4]);
  uint4 r;
  r.x = (unsigned)f2bf(bf2f(w.x & 0xffff) * c0.x) | ((unsigned)f2bf(bf2f(w.x >> 16) * c0.y) << 16);
  r.y = (unsigned)f2bf(bf2f(w.y & 0xffff) * c0.z) | ((unsigned)f2bf(bf2f(w.y >> 16) * c0.w) << 16);
  r.z = (unsigned)f2bf(bf2f(w.z & 0xffff) * c1.x) | ((unsigned)f2bf(bf2f(w.z >> 16) * c1.y) << 16);
  r.w = (unsigned)f2bf(bf2f(w.w & 0xffff) * c1.z) | ((unsigned)f2bf(bf2f(w.w >> 16) * c1.w) << 16);
  *reinterpret_cast<uint4*>(At + base) = r;
}

// ---------------------------------------------------------------------------
extern "C" void kernel_launch(void* const* d_in, const int* in_sizes, int n_in,
                              void* d_out, int out_size, void* d_ws, size_t ws_size,
                              hipStream_t stream){
  (void)in_sizes; (void)n_in; (void)out_size; (void)ws_size;
  const float* x = (const float*)d_in[0];   // (256, 8, 1152)
  const float* W = (const float*)d_in[1];   // (1, 1152, 10, 16, 8)
  float* out = (float*)d_out;               // (256, 10, 16, 1) fp32

  float* s_part = (float*)d_ws;             // 16 * 40960 fp32
  float* bij    = s_part + 16*40960;        // 11520 fp32
  u16* xbp = (u16*)(bij + 11520);           // 2359296 bf16
  u16* xpb = xbp + 2359296;                 // 2359296
  u16* Wt  = xpb + 2359296;                 // 1474560
  u16* At  = Wt  + 1474560;                 // 1474560
  u16* vbt = At  + 1474560;                 // 40960

  k_prep<<<2464, 256, 0, stream>>>(x, W, xbp, xpb, Wt, At, bij);
  for (int it = 0; it < 3; ++it){
    if (it > 0){
      k_g<<<720, 256, 0, stream>>>(xpb, vbt, Wt, bij);
      k_at<<<720, 256, 0, stream>>>(bij, Wt, At);
    }
    k_s<<<dim3(16, 10, 16), 64, 0, stream>>>(xbp, At, s_part);
    k_sq<<<160, 256, 0, stream>>>(s_part, out, vbt);
  }
}